// Round 9
// baseline (436.859 us; speedup 1.0000x reference)
//
#include <hip/hip_runtime.h>
#include <stdint.h>
#include <stddef.h>

// Problem constants (fixed by the reference):
//   x:[B=65536][D=128] f32, E:[C=64][L=64][D=128] f32, counts:[64][64] f32
//   out0 = max_l cos(x_b, E_{c,l})  [B][C]
//   out1 = counts + bincount of argmax_l  [C][L]
#define D      128
#define NCATS  64
#define NLEAF  64
#define NC_BLK 8     // categories per block (c-split x8)
#define BM     512   // rows per block (8 waves x 64 batch cols) — ebuf shared by 8 waves
#define BIAS   32.0f // dot ~ N(0,1) -> biased value positive -> uint order == float order

typedef _Float16 half8_t  __attribute__((ext_vector_type(8)));
typedef _Float16 half4h_t __attribute__((ext_vector_type(4)));
typedef float    float4_t __attribute__((ext_vector_type(4)));

__device__ __forceinline__ void async_ld16(const void* g, void* l) {
  __builtin_amdgcn_global_load_lds((const __attribute__((address_space(1))) uint32_t*)g,
                                   (__attribute__((address_space(3))) uint32_t*)l,
                                   16, 0, 0);
}

// ---------------------------------------------------------------------------
// Prep (R2/R7-verified): E rows -> unit-normalized fp16 with the LDS
// bank-conflict swizzle pre-baked (chunk' = chunk ^ (row&7)) so main staging
// is linear. Also seeds counts_out from the input buffer (d_out is poisoned).
// ---------------------------------------------------------------------------
__global__ __launch_bounds__(256) void prep_e_kernel(const float* __restrict__ e,
                                                     char* __restrict__ e16,
                                                     const float* __restrict__ cin,
                                                     float* __restrict__ counts_out) {
  const int t  = threadIdx.x;
  const int rl = t >> 4;  // row within this block's 16
  const int cc = t & 15;  // 16B chunk (8 halfs) within row
  const int row = blockIdx.x * 16 + rl;
  const float* src = e + (size_t)row * D + cc * 8;
  float4_t v0 = *(const float4_t*)src;
  float4_t v1 = *(const float4_t*)(src + 4);
  float ss = v0.x*v0.x + v0.y*v0.y + v0.z*v0.z + v0.w*v0.w +
             v1.x*v1.x + v1.y*v1.y + v1.z*v1.z + v1.w*v1.w;
  ss += __shfl_xor(ss, 1);
  ss += __shfl_xor(ss, 2);
  ss += __shfl_xor(ss, 4);
  ss += __shfl_xor(ss, 8);
  const float inv = 1.0f / fmaxf(sqrtf(ss), 1e-8f);
  half8_t h;
  h[0] = (_Float16)(v0.x * inv); h[1] = (_Float16)(v0.y * inv);
  h[2] = (_Float16)(v0.z * inv); h[3] = (_Float16)(v0.w * inv);
  h[4] = (_Float16)(v1.x * inv); h[5] = (_Float16)(v1.y * inv);
  h[6] = (_Float16)(v1.z * inv); h[7] = (_Float16)(v1.w * inv);
  const int dc = cc ^ (rl & 7);  // swizzle: row&7 == rl&7 (16-row blocks)
  *(half8_t*)(e16 + (size_t)row * 256 + dc * 16) = h;
  if (blockIdx.x < (NCATS * NLEAF) / 256)
    counts_out[blockIdx.x * 256 + t] = cin[blockIdx.x * 256 + t];
}

// ---------------------------------------------------------------------------
// Main (R8 inner loop verbatim; occupancy/locality restructure):
//  * BM=512: 8 waves share one ebuf -> LDS/wave halves -> 3 blocks/CU =
//    24 waves/CU = 6 waves/SIMD (was 3). Per-wave staging also halves.
//  * XCD swizzle: rb = (bid>>6)*8 + (bid&7), c = (bid>>3)&7 -> the 8 c-split
//    sharers of a row-block have equal bid%8 (same XCD, round-robin) and are
//    8 apart in dispatch -> x-tile (256 KB) L2-resident across all 8 reads.
//  * Operand-swapped MFMA (A=E leaves-on-rows, B=x): argmax is in-lane +
//    xor16/xor32 with explicit temps (R8-verified).
// ---------------------------------------------------------------------------
__global__ __launch_bounds__(512, 6) void main_kernel(const float* __restrict__ x,
                                                      const char* __restrict__ e16,
                                                      float* __restrict__ cos_out,
                                                      float* __restrict__ counts_out) {
  __shared__ __align__(16) char ebuf[2][16384];          // 32 KB, swizzled rows
  __shared__ unsigned hist[NC_BLK * NLEAF];              // 2 KB
  __shared__ __align__(16) _Float16 stage[BM * 8];       // 8 KB, 16 B/row

  const int tid  = threadIdx.x;
  const int w    = tid >> 6;    // wave 0..7
  const int lane = tid & 63;
  const int q    = lane >> 4;   // MFMA quad
  const int wl   = lane & 15;

  // XCD-aware decode (see header comment).
  const int rb     = ((blockIdx.x >> 6) << 3) + (blockIdx.x & 7);
  const int c_base = ((blockIdx.x >> 3) & 7) * NC_BLK;
  const int b_base = rb * BM;

  for (int i = tid; i < NC_BLK * NLEAF; i += 512) hist[i] = 0;

  // Prefetch first E tile (category c_base) into ebuf[0]: linear 16KB copy,
  // 2 KB per wave (8 waves).
  {
    const char* g = e16 + (size_t)c_base * 16384 + w * 2048 + lane * 16;
    char* l = &ebuf[0][w * 2048 + lane * 16];
#pragma unroll
    for (int j = 0; j < 2; ++j) async_ld16(g + j * 1024, l + j * 1024);
  }

  // B = x fragments (verified lane layout: B[n=lane&15][k=quad*8+j]):
  // tile nt covers batch rows b_base + w*64 + nt*16 + [0,16).
  half8_t bfrag[4][4];
  float inv_x[4];
#pragma unroll
  for (int nt = 0; nt < 4; ++nt) {
    const int row = b_base + w * 64 + nt * 16 + wl;
    const float* xr = x + (size_t)row * D;
    float ss = 0.f;
#pragma unroll
    for (int s = 0; s < 4; ++s) {
      const float* p = xr + s * 32 + q * 8;
      float4_t v0 = *(const float4_t*)p;
      float4_t v1 = *(const float4_t*)(p + 4);
      half8_t h;
      h[0] = (_Float16)v0.x; h[1] = (_Float16)v0.y;
      h[2] = (_Float16)v0.z; h[3] = (_Float16)v0.w;
      h[4] = (_Float16)v1.x; h[5] = (_Float16)v1.y;
      h[6] = (_Float16)v1.z; h[7] = (_Float16)v1.w;
      bfrag[nt][s] = h;
      ss += v0.x*v0.x + v0.y*v0.y + v0.z*v0.z + v0.w*v0.w +
            v1.x*v1.x + v1.y*v1.y + v1.z*v1.z + v1.w*v1.w;
    }
    ss += __shfl_xor(ss, 16);  // sum across the 4 quads holding this row
    ss += __shfl_xor(ss, 32);
    inv_x[nt] = 1.0f / fmaxf(sqrtf(ss), 1e-8f);
  }

  // A = E LDS addresses (rt = leaf tile): row (rt*16+wl), chunk
  // (q+4s)^(wl&7) [prep pre-swizzled].
  int rowbase[4], xoff[4];
#pragma unroll
  for (int rt = 0; rt < 4; ++rt) rowbase[rt] = (rt * 16 + wl) * 256;
#pragma unroll
  for (int s = 0; s < 4; ++s) xoff[s] = ((q + 4 * s) ^ (wl & 7)) * 16;

  const unsigned idq = (unsigned)(q << 2);  // leaf-index bits {2,3} (lane const)
  const float4_t bias4 = {BIAS, BIAS, BIAS, BIAS};

  __syncthreads();  // drains prefetch vmcnt + hist init

  for (int ci = 0; ci < NC_BLK; ++ci) {
    const char* cur = ebuf[ci & 1];

    if (ci + 1 < NC_BLK) {  // async prefetch next tile; drained at end barrier
      const char* g = e16 + (size_t)(c_base + ci + 1) * 16384 + w * 2048 + lane * 16;
      char* l = &ebuf[(ci + 1) & 1][w * 2048 + lane * 16];
#pragma unroll
      for (int j = 0; j < 2; ++j) async_ld16(g + j * 1024, l + j * 1024);
    }

    // rt-outer: acc[4] (one per batch tile nt) live at a time. C/D layout:
    // col = lane&15 = batch-within-tile, row = q*4+reg = leaf-within-tile.
    // Keys carry leaf idx bits {0,1}=reg, {4,5}=rt at pack time; bits {2,3}
    // (=q) are zero in-lane and OR'd once before the cross-lane combine.
    unsigned pk[4];
#pragma unroll
    for (int rt = 0; rt < 4; ++rt) {
      float4_t acc[4];
#pragma unroll
      for (int s = 0; s < 4; ++s) {
        half8_t ef = *(const half8_t*)(cur + rowbase[rt] + xoff[s]);
#pragma unroll
        for (int nt = 0; nt < 4; ++nt)
          acc[nt] = __builtin_amdgcn_mfma_f32_16x16x32_f16(
              ef, bfrag[nt][s], (s == 0) ? bias4 : acc[nt], 0, 0, 0);
      }
#pragma unroll
      for (int nt = 0; nt < 4; ++nt)
#pragma unroll
        for (int reg = 0; reg < 4; ++reg) {
          unsigned k = (__float_as_uint(acc[nt][reg]) & 0xFFFFFFC0u) |
                       (unsigned)(rt * 16 + reg);
          if (rt == 0 && reg == 0) pk[nt] = k;
          else                     pk[nt] = (pk[nt] > k) ? pk[nt] : k;
        }
    }

    // Cross-lane: combine the 4 quads of this batch col. EXPLICIT TEMPS,
    // unconditional shuffles (R3 lesson: never a cross-lane op in a ternary).
#pragma unroll
    for (int nt = 0; nt < 4; ++nt) {
      unsigned v = pk[nt] | idq;
      unsigned t = (unsigned)__shfl_xor((int)v, 16);
      v = (v > t) ? v : t;
      t = (unsigned)__shfl_xor((int)v, 32);
      v = (v > t) ? v : t;
      pk[nt] = v;
    }

    // Writers: lanes 0..15 (q=0) own batch col nt*16+lane for all nt, and
    // hold the matching inv_x[nt] (their own wl == lane).
    if (lane < 16) {
#pragma unroll
      for (int nt = 0; nt < 4; ++nt) {
        const unsigned p = pk[nt];
        const float val = (__uint_as_float(p & 0xFFFFFFC0u) - BIAS) * inv_x[nt];
        stage[(w * 64 + nt * 16 + lane) * 8 + ci] = (_Float16)val;
        atomicAdd(&hist[ci * NLEAF + (int)(p & 63u)], 1u);
      }
    }
    __syncthreads();  // protects ebuf reuse + drains prefetch
  }

  __syncthreads();  // stage writes visible to all

  // Coalesced cos flush: rows [b_base,+512) x cols [c_base,+8).
  // stage byte addr = 8*id -> contiguous b64 reads, conflict-free.
#pragma unroll
  for (int k = 0; k < 2; ++k) {
    const int id = k * 512 + tid;
    const int r  = id >> 1;
    const int c0 = (id & 1) * 4;
    half4h_t h = *(const half4h_t*)&stage[r * 8 + c0];
    float4_t v;
    v.x = (float)h[0]; v.y = (float)h[1]; v.z = (float)h[2]; v.w = (float)h[3];
    *(float4_t*)&cos_out[(size_t)(b_base + r) * NCATS + c_base + c0] = v;
  }

  // Flush histogram (exact: integer-valued float atomics).
  for (int i = tid; i < NC_BLK * NLEAF; i += 512) {
    const unsigned v = hist[i];
    if (v) atomicAdd(&counts_out[c_base * NLEAF + i], (float)v);
  }
}

extern "C" void kernel_launch(void* const* d_in, const int* in_sizes, int n_in,
                              void* d_out, int out_size, void* d_ws, size_t ws_size,
                              hipStream_t stream) {
  const float* x   = (const float*)d_in[0];
  const float* e   = (const float*)d_in[1];
  const float* cin = (const float*)d_in[2];

  const int B = in_sizes[0] / D;                 // 65536
  const int erows = in_sizes[1] / D;             // 4096
  float* cos_out = (float*)d_out;                // [B][64]
  float* counts_out = cos_out + (size_t)B * NCATS;
  char* e16 = (char*)d_ws;                       // 4096*256B = 1 MB swizzled fp16 E

  prep_e_kernel<<<erows / 16, 256, 0, stream>>>(e, e16, cin, counts_out);
  main_kernel<<<(B / BM) * (NCATS / NC_BLK), 512, 0, stream>>>(x, e16, cos_out, counts_out);
}

// Round 10
// 147.663 us; speedup vs baseline: 2.9585x; 2.9585x over previous
//
#include <hip/hip_runtime.h>
#include <stdint.h>
#include <stddef.h>

// Problem constants (fixed by the reference):
//   x:[B=65536][D=128] f32, E:[C=64][L=64][D=128] f32, counts:[64][64] f32
//   out0 = max_l cos(x_b, E_{c,l})  [B][C]
//   out1 = counts + bincount of argmax_l  [C][L]
#define D      128
#define NCATS  64
#define NLEAF  64
#define NC_BLK 8     // categories per block (c-split x8)
#define BM     512   // rows per block (8 waves x 64 batch cols) — ebuf shared by 8 waves
#define BIAS   32.0f // dot ~ N(0,1) -> biased value positive -> uint order == float order

typedef _Float16 half8_t  __attribute__((ext_vector_type(8)));
typedef _Float16 half4h_t __attribute__((ext_vector_type(4)));
typedef float    float4_t __attribute__((ext_vector_type(4)));

__device__ __forceinline__ void async_ld16(const void* g, void* l) {
  __builtin_amdgcn_global_load_lds((const __attribute__((address_space(1))) uint32_t*)g,
                                   (__attribute__((address_space(3))) uint32_t*)l,
                                   16, 0, 0);
}

// ---------------------------------------------------------------------------
// Prep (R2/R7-verified): E rows -> unit-normalized fp16 with the LDS
// bank-conflict swizzle pre-baked (chunk' = chunk ^ (row&7)) so main staging
// is linear. Also seeds counts_out from the input buffer (d_out is poisoned).
// ---------------------------------------------------------------------------
__global__ __launch_bounds__(256) void prep_e_kernel(const float* __restrict__ e,
                                                     char* __restrict__ e16,
                                                     const float* __restrict__ cin,
                                                     float* __restrict__ counts_out) {
  const int t  = threadIdx.x;
  const int rl = t >> 4;  // row within this block's 16
  const int cc = t & 15;  // 16B chunk (8 halfs) within row
  const int row = blockIdx.x * 16 + rl;
  const float* src = e + (size_t)row * D + cc * 8;
  float4_t v0 = *(const float4_t*)src;
  float4_t v1 = *(const float4_t*)(src + 4);
  float ss = v0.x*v0.x + v0.y*v0.y + v0.z*v0.z + v0.w*v0.w +
             v1.x*v1.x + v1.y*v1.y + v1.z*v1.z + v1.w*v1.w;
  ss += __shfl_xor(ss, 1);
  ss += __shfl_xor(ss, 2);
  ss += __shfl_xor(ss, 4);
  ss += __shfl_xor(ss, 8);
  const float inv = 1.0f / fmaxf(sqrtf(ss), 1e-8f);
  half8_t h;
  h[0] = (_Float16)(v0.x * inv); h[1] = (_Float16)(v0.y * inv);
  h[2] = (_Float16)(v0.z * inv); h[3] = (_Float16)(v0.w * inv);
  h[4] = (_Float16)(v1.x * inv); h[5] = (_Float16)(v1.y * inv);
  h[6] = (_Float16)(v1.z * inv); h[7] = (_Float16)(v1.w * inv);
  const int dc = cc ^ (rl & 7);  // swizzle: row&7 == rl&7 (16-row blocks)
  *(half8_t*)(e16 + (size_t)row * 256 + dc * 16) = h;
  if (blockIdx.x < (NCATS * NLEAF) / 256)
    counts_out[blockIdx.x * 256 + t] = cin[blockIdx.x * 256 + t];
}

// ---------------------------------------------------------------------------
// Main (R9 structure, register fix):
//  * __launch_bounds__(512,3): empirical rule across R5/R6/R7/R9 — achieved
//    VGPR cap ~= 256/arg. (512,6) capped at 40 VGPR -> ~1 GB spill traffic.
//    arg=3 -> cap ~85 >= the ~60 this kernel naturally uses. DO NOT RAISE.
//  * BM=512: 8 waves share one ebuf -> 43 KB LDS -> 3 blocks/CU = 6 waves/SIMD
//    (R9 measured occupancy 58% with this shape).
//  * XCD swizzle: rb = (bid>>6)*8 + (bid&7), c = (bid>>3)&7 -> the 8 c-split
//    sharers of a row-block land on one XCD -> x-tile L2-resident.
//  * Operand-swapped MFMA (A=E leaves-on-rows, B=x): argmax in-lane +
//    xor16/xor32 with explicit temps (R8-verified).
// ---------------------------------------------------------------------------
__global__ __launch_bounds__(512, 3) void main_kernel(const float* __restrict__ x,
                                                      const char* __restrict__ e16,
                                                      float* __restrict__ cos_out,
                                                      float* __restrict__ counts_out) {
  __shared__ __align__(16) char ebuf[2][16384];          // 32 KB, swizzled rows
  __shared__ unsigned hist[NC_BLK * NLEAF];              // 2 KB
  __shared__ __align__(16) _Float16 stage[BM * 8];       // 8 KB, 16 B/row

  const int tid  = threadIdx.x;
  const int w    = tid >> 6;    // wave 0..7
  const int lane = tid & 63;
  const int q    = lane >> 4;   // MFMA quad
  const int wl   = lane & 15;

  // XCD-aware decode (see header comment).
  const int rb     = ((blockIdx.x >> 6) << 3) + (blockIdx.x & 7);
  const int c_base = ((blockIdx.x >> 3) & 7) * NC_BLK;
  const int b_base = rb * BM;

  for (int i = tid; i < NC_BLK * NLEAF; i += 512) hist[i] = 0;

  // Prefetch first E tile (category c_base) into ebuf[0]: linear 16KB copy,
  // 2 KB per wave (8 waves).
  {
    const char* g = e16 + (size_t)c_base * 16384 + w * 2048 + lane * 16;
    char* l = &ebuf[0][w * 2048 + lane * 16];
#pragma unroll
    for (int j = 0; j < 2; ++j) async_ld16(g + j * 1024, l + j * 1024);
  }

  // B = x fragments (verified lane layout: B[n=lane&15][k=quad*8+j]):
  // tile nt covers batch rows b_base + w*64 + nt*16 + [0,16).
  half8_t bfrag[4][4];
  float inv_x[4];
#pragma unroll
  for (int nt = 0; nt < 4; ++nt) {
    const int row = b_base + w * 64 + nt * 16 + wl;
    const float* xr = x + (size_t)row * D;
    float ss = 0.f;
#pragma unroll
    for (int s = 0; s < 4; ++s) {
      const float* p = xr + s * 32 + q * 8;
      float4_t v0 = *(const float4_t*)p;
      float4_t v1 = *(const float4_t*)(p + 4);
      half8_t h;
      h[0] = (_Float16)v0.x; h[1] = (_Float16)v0.y;
      h[2] = (_Float16)v0.z; h[3] = (_Float16)v0.w;
      h[4] = (_Float16)v1.x; h[5] = (_Float16)v1.y;
      h[6] = (_Float16)v1.z; h[7] = (_Float16)v1.w;
      bfrag[nt][s] = h;
      ss += v0.x*v0.x + v0.y*v0.y + v0.z*v0.z + v0.w*v0.w +
            v1.x*v1.x + v1.y*v1.y + v1.z*v1.z + v1.w*v1.w;
    }
    ss += __shfl_xor(ss, 16);  // sum across the 4 quads holding this row
    ss += __shfl_xor(ss, 32);
    inv_x[nt] = 1.0f / fmaxf(sqrtf(ss), 1e-8f);
  }

  // A = E LDS addresses (rt = leaf tile): row (rt*16+wl), chunk
  // (q+4s)^(wl&7) [prep pre-swizzled].
  int rowbase[4], xoff[4];
#pragma unroll
  for (int rt = 0; rt < 4; ++rt) rowbase[rt] = (rt * 16 + wl) * 256;
#pragma unroll
  for (int s = 0; s < 4; ++s) xoff[s] = ((q + 4 * s) ^ (wl & 7)) * 16;

  const unsigned idq = (unsigned)(q << 2);  // leaf-index bits {2,3} (lane const)
  const float4_t bias4 = {BIAS, BIAS, BIAS, BIAS};

  __syncthreads();  // drains prefetch vmcnt + hist init

  for (int ci = 0; ci < NC_BLK; ++ci) {
    const char* cur = ebuf[ci & 1];

    if (ci + 1 < NC_BLK) {  // async prefetch next tile; drained at end barrier
      const char* g = e16 + (size_t)(c_base + ci + 1) * 16384 + w * 2048 + lane * 16;
      char* l = &ebuf[(ci + 1) & 1][w * 2048 + lane * 16];
#pragma unroll
      for (int j = 0; j < 2; ++j) async_ld16(g + j * 1024, l + j * 1024);
    }

    // rt-outer: acc[4] (one per batch tile nt) live at a time. C/D layout:
    // col = lane&15 = batch-within-tile, row = q*4+reg = leaf-within-tile.
    // Keys carry leaf idx bits {0,1}=reg, {4,5}=rt at pack time; bits {2,3}
    // (=q) are zero in-lane and OR'd once before the cross-lane combine.
    unsigned pk[4];
#pragma unroll
    for (int rt = 0; rt < 4; ++rt) {
      float4_t acc[4];
#pragma unroll
      for (int s = 0; s < 4; ++s) {
        half8_t ef = *(const half8_t*)(cur + rowbase[rt] + xoff[s]);
#pragma unroll
        for (int nt = 0; nt < 4; ++nt)
          acc[nt] = __builtin_amdgcn_mfma_f32_16x16x32_f16(
              ef, bfrag[nt][s], (s == 0) ? bias4 : acc[nt], 0, 0, 0);
      }
#pragma unroll
      for (int nt = 0; nt < 4; ++nt)
#pragma unroll
        for (int reg = 0; reg < 4; ++reg) {
          unsigned k = (__float_as_uint(acc[nt][reg]) & 0xFFFFFFC0u) |
                       (unsigned)(rt * 16 + reg);
          if (rt == 0 && reg == 0) pk[nt] = k;
          else                     pk[nt] = (pk[nt] > k) ? pk[nt] : k;
        }
    }

    // Cross-lane: combine the 4 quads of this batch col. EXPLICIT TEMPS,
    // unconditional shuffles (R3 lesson: never a cross-lane op in a ternary).
#pragma unroll
    for (int nt = 0; nt < 4; ++nt) {
      unsigned v = pk[nt] | idq;
      unsigned t = (unsigned)__shfl_xor((int)v, 16);
      v = (v > t) ? v : t;
      t = (unsigned)__shfl_xor((int)v, 32);
      v = (v > t) ? v : t;
      pk[nt] = v;
    }

    // Writers: lanes 0..15 (q=0) own batch col nt*16+lane for all nt, and
    // hold the matching inv_x[nt] (their own wl == lane).
    if (lane < 16) {
#pragma unroll
      for (int nt = 0; nt < 4; ++nt) {
        const unsigned p = pk[nt];
        const float val = (__uint_as_float(p & 0xFFFFFFC0u) - BIAS) * inv_x[nt];
        stage[(w * 64 + nt * 16 + lane) * 8 + ci] = (_Float16)val;
        atomicAdd(&hist[ci * NLEAF + (int)(p & 63u)], 1u);
      }
    }
    __syncthreads();  // protects ebuf reuse + drains prefetch
  }

  __syncthreads();  // stage writes visible to all

  // Coalesced cos flush: rows [b_base,+512) x cols [c_base,+8).
  // stage byte addr = 8*id -> contiguous b64 reads, conflict-free.
#pragma unroll
  for (int k = 0; k < 2; ++k) {
    const int id = k * 512 + tid;
    const int r  = id >> 1;
    const int c0 = (id & 1) * 4;
    half4h_t h = *(const half4h_t*)&stage[r * 8 + c0];
    float4_t v;
    v.x = (float)h[0]; v.y = (float)h[1]; v.z = (float)h[2]; v.w = (float)h[3];
    *(float4_t*)&cos_out[(size_t)(b_base + r) * NCATS + c_base + c0] = v;
  }

  // Flush histogram (exact: integer-valued float atomics).
  for (int i = tid; i < NC_BLK * NLEAF; i += 512) {
    const unsigned v = hist[i];
    if (v) atomicAdd(&counts_out[c_base * NLEAF + i], (float)v);
  }
}

extern "C" void kernel_launch(void* const* d_in, const int* in_sizes, int n_in,
                              void* d_out, int out_size, void* d_ws, size_t ws_size,
                              hipStream_t stream) {
  const float* x   = (const float*)d_in[0];
  const float* e   = (const float*)d_in[1];
  const float* cin = (const float*)d_in[2];

  const int B = in_sizes[0] / D;                 // 65536
  const int erows = in_sizes[1] / D;             // 4096
  float* cos_out = (float*)d_out;                // [B][64]
  float* counts_out = cos_out + (size_t)B * NCATS;
  char* e16 = (char*)d_ws;                       // 4096*256B = 1 MB swizzled fp16 E

  prep_e_kernel<<<erows / 16, 256, 0, stream>>>(e, e16, cin, counts_out);
  main_kernel<<<(B / BM) * (NCATS / NC_BLK), 512, 0, stream>>>(x, e16, cos_out, counts_out);
}